// Round 1
// baseline (10411.970 us; speedup 1.0000x reference)
//
#include <hip/hip_runtime.h>
#include <math.h>

#define Bv 8
#define Tv 16
#define Hv 64
#define Wv 64
#define Cv 16
#define HID 64
// gate channels = 4*HID = 256

__device__ __forceinline__ float sigmoid_f(float x) {
  return 1.f / (1.f + __expf(-x));
}
// NaN-safe tanh: 1 - 2/(e^{2x}+1); e=inf -> 1, e=0 -> -1
__device__ __forceinline__ float tanh_f(float x) {
  float e = __expf(2.f * x);
  return 1.f - 2.f / (e + 1.f);
}

// One ConvLSTM cell step, fused conv(3x3 SAME over concat[src0,src1]) + gates.
// Block: 4x4 pixel tile, 256 threads (thread = gate channel).
// src0: [B,H,W,C0] (batch stride s0_bstride elements), src1: [B,H,W,CIN-C0]
// cbuf: c state in/out (in-place), hnew: new h out. All fp32.
template<int CIN, int C0>
__global__ __launch_bounds__(256)
void lstm_step(const float* __restrict__ src0, int s0_bstride,
               const float* __restrict__ src1,
               const float* __restrict__ Wk, const float* __restrict__ bk,
               float* __restrict__ cbuf, float* __restrict__ hnew)
{
  constexpr int C1 = CIN - C0;
  constexpr int PATCH = 36 * CIN;          // 6x6 spatial x CIN
  constexpr int SM = (PATCH > 16 * 256) ? PATCH : 16 * 256;
  __shared__ float smem[SM];
  float* patch = smem;                      // phase 1
  float* zs    = smem;                      // phase 2 (aliased, sync'd)

  const int tid = threadIdx.x;
  const int bx = blockIdx.x, by = blockIdx.y, b = blockIdx.z;
  const int y0 = by * 4 - 1, x0 = bx * 4 - 1;

  // ---- stage 6x6xCIN zero-padded patch into LDS ----
  for (int idx = tid; idx < PATCH; idx += 256) {
    int pp = idx / CIN, ci = idx - pp * CIN;
    int py = pp / 6, px = pp - py * 6;
    int gy = y0 + py, gx = x0 + px;
    float v = 0.f;
    if (gy >= 0 && gy < Hv && gx >= 0 && gx < Wv) {
      if (ci < C0)
        v = src0[(size_t)b * s0_bstride + (gy * Wv + gx) * C0 + ci];
      else
        v = src1[((size_t)((b * Hv + gy) * Wv) + gx) * C1 + (ci - C0)];
    }
    patch[idx] = v;
  }
  __syncthreads();

  // ---- implicit GEMM: each thread computes gate channel `gc` for 16 pixels ----
  const int gc = tid;
  float acc[16];
#pragma unroll
  for (int p = 0; p < 16; ++p) acc[p] = 0.f;

#pragma unroll
  for (int ky = 0; ky < 3; ++ky) {
    for (int c4 = 0; c4 < CIN / 4; ++c4) {
      // weights for the 3 kx taps, 4 input channels each (coalesced over gc)
      float4 wv[3];
#pragma unroll
      for (int kx = 0; kx < 3; ++kx) {
        const float* wp = Wk + ((size_t)((ky * 3 + kx) * CIN + c4 * 4)) * 256 + gc;
        wv[kx].x = wp[0];
        wv[kx].y = wp[256];
        wv[kx].z = wp[512];
        wv[kx].w = wp[768];
      }
#pragma unroll
      for (int py = 0; py < 4; ++py) {
        float4 pr[6];  // 6 horizontal pixels cover all (px,kx) combos
#pragma unroll
        for (int u = 0; u < 6; ++u)
          pr[u] = *(const float4*)&patch[((py + ky) * 6 + u) * CIN + c4 * 4];
#pragma unroll
        for (int kx = 0; kx < 3; ++kx) {
#pragma unroll
          for (int px = 0; px < 4; ++px) {
            float4 pv = pr[px + kx];
            float4 w = wv[kx];
            acc[py * 4 + px] += pv.x * w.x + pv.y * w.y + pv.z * w.z + pv.w * w.w;
          }
        }
      }
    }
  }

  const float bias = bk[gc];
  __syncthreads();   // done reading patch (zs aliases it)
#pragma unroll
  for (int p = 0; p < 16; ++p) zs[p * 256 + gc] = acc[p] + bias;
  __syncthreads();

  // ---- gates: 64 lanes = hid channel j, 4 groups handle 4 pixels per pass ----
  const int j = tid & 63, pq = tid >> 6;
#pragma unroll
  for (int pass = 0; pass < 4; ++pass) {
    int p = pass * 4 + pq;
    float iv = zs[p * 256 + j];
    float fv = zs[p * 256 + 64 + j];
    float ov = zs[p * 256 + 128 + j];
    float gv = zs[p * 256 + 192 + j];
    int py = p >> 2, px = p & 3;
    int gy = by * 4 + py, gx = bx * 4 + px;
    size_t base = ((size_t)((b * Hv + gy) * Wv) + gx) * HID + j;
    float co = cbuf[base];
    float cn = sigmoid_f(fv) * co + sigmoid_f(iv) * tanh_f(gv);
    float hn = sigmoid_f(ov) * tanh_f(cn);
    cbuf[base] = cn;
    hnew[base] = hn;
  }
}

extern "C" void kernel_launch(void* const* d_in, const int* in_sizes, int n_in,
                              void* d_out, int out_size, void* d_ws, size_t ws_size,
                              hipStream_t stream) {
  const float* enc = (const float*)d_in[0];
  const float* W0  = (const float*)d_in[1];
  const float* b0  = (const float*)d_in[2];
  const float* W1  = (const float*)d_in[3];
  const float* b1  = (const float*)d_in[4];

  float* out = (float*)d_out;
  const size_t NSTATE = (size_t)Bv * Hv * Wv * HID;   // 2,097,152 elements
  float* h1_out = out;                                 // final h1
  float* c1     = out + NSTATE;                        // c1, updated in place

  const size_t NB = NSTATE * sizeof(float);            // 8 MB
  char* ws = (char*)d_ws;
  float* h0a = (float*)(ws);                           // zero-init
  float* c0  = (float*)(ws + NB);                      // zero-init
  float* h0b = (float*)(ws + 2 * NB);
  float* h1b = (float*)(ws + 3 * NB);

  // zero: h0a, c0 (contiguous), and d_out (h1 t=0 read buffer + c1)
  hipMemsetAsync(ws, 0, 2 * NB, stream);
  hipMemsetAsync(d_out, 0, 2 * NSTATE * sizeof(float), stream);

  dim3 grid(Wv / 4, Hv / 4, Bv), block(256);
  const int xb_stride = Tv * Hv * Wv * Cv;             // enc batch stride
  const int hb_stride = Hv * Wv * HID;                 // h batch stride

  for (int t = 0; t < Tv; ++t) {
    const float* x_t = enc + (size_t)t * Hv * Wv * Cv;
    float* h0r = (t & 1) ? h0b : h0a;
    float* h0w = (t & 1) ? h0a : h0b;
    // h1 ping-pong arranged so t=15 (odd) writes h1_out; t=0 reads zeroed h1_out
    float* h1r = (t & 1) ? h1b : h1_out;
    float* h1w = (t & 1) ? h1_out : h1b;

    lstm_step<Cv + HID, Cv><<<grid, block, 0, stream>>>(
        x_t, xb_stride, h0r, W0, b0, c0, h0w);
    lstm_step<2 * HID, HID><<<grid, block, 0, stream>>>(
        h0w, hb_stride, h1r, W1, b1, c1, h1w);
  }
}

// Round 2
// 1710.586 us; speedup vs baseline: 6.0868x; 6.0868x over previous
//
#include <hip/hip_runtime.h>
#include <hip/hip_bf16.h>

#define Bv 8
#define Tv 16
#define Hv 64
#define Wv 64
#define Cv 16
#define HID 64
#define PH 66   // spatially padded (1-px halo)

typedef short short8 __attribute__((ext_vector_type(8)));
typedef float f32x4 __attribute__((ext_vector_type(4)));
typedef unsigned short u16x8 __attribute__((ext_vector_type(8)));

__device__ __forceinline__ unsigned short f2bf(float x) {
  union { float f; unsigned int u; } v; v.f = x;
  unsigned int r = v.u + 0x7FFF + ((v.u >> 16) & 1);   // RNE
  return (unsigned short)(r >> 16);
}
__device__ __forceinline__ float sigmoid_f(float x) {
  return 1.f / (1.f + __expf(-x));
}
__device__ __forceinline__ float tanh_f(float x) {
  float e = __expf(2.f * x);
  return 1.f - 2.f / (e + 1.f);
}

// ---- x pre-convert: enc[b,t,y,x,0:16] fp32 -> padded bf16 [b][66][66][32] (ch16..31 = 0)
__global__ void convert_x(const float* __restrict__ enc_t, unsigned short* __restrict__ xb) {
  int idx = blockIdx.x * 256 + threadIdx.x;          // 32768 = b*4096 + pix
  int b = idx >> 12, pix = idx & 4095;
  int y = pix >> 6, x = pix & 63;
  const float* s = enc_t + (size_t)b * (Tv * Hv * Wv * Cv) + (size_t)pix * Cv;
  float4 f0 = *(const float4*)(s);
  float4 f1 = *(const float4*)(s + 4);
  float4 f2 = *(const float4*)(s + 8);
  float4 f3 = *(const float4*)(s + 12);
  u16x8 o0, o1, z = {};
  o0[0]=f2bf(f0.x); o0[1]=f2bf(f0.y); o0[2]=f2bf(f0.z); o0[3]=f2bf(f0.w);
  o0[4]=f2bf(f1.x); o0[5]=f2bf(f1.y); o0[6]=f2bf(f1.z); o0[7]=f2bf(f1.w);
  o1[0]=f2bf(f2.x); o1[1]=f2bf(f2.y); o1[2]=f2bf(f2.z); o1[3]=f2bf(f2.w);
  o1[4]=f2bf(f3.x); o1[5]=f2bf(f3.y); o1[6]=f2bf(f3.z); o1[7]=f2bf(f3.w);
  unsigned short* d = xb + ((size_t)((b * PH + y + 1) * PH) + (x + 1)) * 32;
  *(u16x8*)(d)      = o0;
  *(u16x8*)(d + 8)  = o1;
  *(u16x8*)(d + 16) = z;
  *(u16x8*)(d + 24) = z;
}

// ---- weight re-layouts: fp32 [3,3,CI,256] -> bf16 [chunk][col'][32]
// col' = wn*64 + g*16 + c  <->  orig col = g*64 + wn*16 + c   (wave-local gate fusion)
__global__ void relayout_w0(const float* __restrict__ W0, unsigned short* __restrict__ out) {
  int o = blockIdx.x * 256 + threadIdx.x;            // 27*8192 = 221184
  if (o >= 27 * 8192) return;
  int chunk = o >> 13, rem = o & 8191;
  int colp = rem >> 5, kk = rem & 31;
  int tap = chunk / 3, cg = chunk - tap * 3;
  int wn = colp >> 6, g = (colp >> 4) & 3, c = colp & 15;
  int col = g * 64 + wn * 16 + c;
  int p = cg * 32 + kk;                              // padded ci: 0..15 x, 16..31 pad, 32..95 h
  float v = 0.f;
  if (p < 16)        v = W0[(size_t)(tap * 80 + p) * 256 + col];
  else if (p >= 32)  v = W0[(size_t)(tap * 80 + (p - 16)) * 256 + col];
  out[o] = f2bf(v);
}
__global__ void relayout_w1(const float* __restrict__ W1, unsigned short* __restrict__ out) {
  int o = blockIdx.x * 256 + threadIdx.x;            // 36*8192 = 294912
  if (o >= 36 * 8192) return;
  int chunk = o >> 13, rem = o & 8191;
  int colp = rem >> 5, kk = rem & 31;
  int tap = chunk >> 2, cg = chunk & 3;
  int wn = colp >> 6, g = (colp >> 4) & 3, c = colp & 15;
  int col = g * 64 + wn * 16 + c;
  out[o] = f2bf(W1[(size_t)(tap * 128 + cg * 32 + kk) * 256 + col]);
}

// ---- fused ConvLSTM cell step: implicit-GEMM MFMA + gates.
// Block: 128 pixels (16x8 tile) x 256 gate-cols, 8 waves (wave = 64 px x 16 hid x 4 gates).
// CELL=0: A0 = x_bf (32ch), A1 = h0 (64ch), 27 chunks.
// CELL=1: A0 = h0 (64ch),  A1 = h1 (64ch), 36 chunks.
template<int CELL>
__global__ __launch_bounds__(512, 2)
void cell_mfma(const unsigned short* __restrict__ A0, const unsigned short* __restrict__ A1,
               const unsigned short* __restrict__ Wr, const float* __restrict__ bias,
               float* __restrict__ cbuf, unsigned short* __restrict__ hout,
               float* __restrict__ hf32) {
  constexpr int CG = (CELL == 0) ? 3 : 4;
  constexpr int NC = 9 * CG;

  const int tid = threadIdx.x;
  const int l = tid & 63, w = tid >> 6;
  const int wm = w >> 2, wn = w & 3;
  const int bx = blockIdx.x, by = blockIdx.y, b = blockIdx.z;
  const int r = l & 15, kg = l >> 4;

  const char* bases[2] = {(const char*)A0, (const char*)A1};
  unsigned int offs[CG][4];
#pragma unroll
  for (int mi = 0; mi < 4; ++mi) {
    int p = wm * 64 + mi * 16 + r;
    int y = by * 16 + (p >> 3), x = bx * 8 + (p & 7);
    int pix = (b * PH + y) * PH + x;                 // tap(0,0) in padded coords
#pragma unroll
    for (int cg = 0; cg < CG; ++cg) {
      int chb = (CELL == 0) ? (cg == 0 ? 64 : 128) : 128;   // bytes per pixel-row
      int cho = (CELL == 0) ? (cg == 2 ? 64 : 0) : ((cg & 1) * 64);
      offs[cg][mi] = (unsigned)(pix * chb + cho + kg * 16);
    }
  }
  const unsigned int boff = (unsigned)((wn * 64 + r) * 64 + kg * 16);

  f32x4 acc[4][4] = {};
  short8 af[2][4], bfv[2][4];

  auto LD = [&](int cc, int pp) {
    int tap = cc / CG, cg = cc - tap * CG;
    int ky = tap / 3, kx = tap - ky * 3;
    int chb = (CELL == 0) ? (cg == 0 ? 64 : 128) : 128;
    int bs  = (CELL == 0) ? (cg == 0 ? 0 : 1) : (cg >> 1);
    unsigned int toff = (unsigned)((ky * PH + kx) * chb);
#pragma unroll
    for (int mi = 0; mi < 4; ++mi)
      af[pp][mi] = *(const short8*)(bases[bs] + offs[cg][mi] + toff);
    const char* wp = (const char*)Wr + (size_t)cc * 16384 + boff;
#pragma unroll
    for (int g = 0; g < 4; ++g)
      bfv[pp][g] = *(const short8*)(wp + g * 1024);
  };

  LD(0, 0);
#pragma unroll
  for (int cc = 0; cc < NC; ++cc) {
    if (cc + 1 < NC) LD(cc + 1, (cc + 1) & 1);
    const int pp = cc & 1;
#pragma unroll
    for (int mi = 0; mi < 4; ++mi)
#pragma unroll
      for (int g = 0; g < 4; ++g)
        acc[mi][g] = __builtin_amdgcn_mfma_f32_16x16x32_bf16(
            af[pp][mi], bfv[pp][g], acc[mi][g], 0, 0, 0);
  }

  // ---- gates (wave-local: this wave owns hid j = wn*16 + r, all 4 gates)
  const int j = wn * 16 + r;
  float bi[4];
#pragma unroll
  for (int g = 0; g < 4; ++g) bi[g] = bias[g * 64 + j];

#pragma unroll
  for (int mi = 0; mi < 4; ++mi) {
#pragma unroll
    for (int rg = 0; rg < 4; ++rg) {
      int p = wm * 64 + mi * 16 + kg * 4 + rg;       // C/D row = (lane>>4)*4 + reg
      int y = by * 16 + (p >> 3), x = bx * 8 + (p & 7);
      size_t ci = ((size_t)((b * Hv + y) * Wv) + x) * HID + j;
      float zi = acc[mi][0][rg] + bi[0];
      float zf = acc[mi][1][rg] + bi[1];
      float zo = acc[mi][2][rg] + bi[2];
      float zg = acc[mi][3][rg] + bi[3];
      float co = cbuf[ci];
      float cn = sigmoid_f(zf) * co + sigmoid_f(zi) * tanh_f(zg);
      float hn = sigmoid_f(zo) * tanh_f(cn);
      cbuf[ci] = cn;
      hout[((size_t)((b * PH + y + 1) * PH) + (x + 1)) * HID + j] = f2bf(hn);
      if (hf32) hf32[ci] = hn;
    }
  }
}

extern "C" void kernel_launch(void* const* d_in, const int* in_sizes, int n_in,
                              void* d_out, int out_size, void* d_ws, size_t ws_size,
                              hipStream_t stream) {
  const float* enc = (const float*)d_in[0];
  const float* W0  = (const float*)d_in[1];
  const float* b0  = (const float*)d_in[2];
  const float* W1  = (const float*)d_in[3];
  const float* b1  = (const float*)d_in[4];

  float* out = (float*)d_out;
  const size_t NST = (size_t)Bv * Hv * Wv * HID;     // 2,097,152
  float* h1f = out;                                   // final h1 (fp32)
  float* c1  = out + NST;                             // c1 state, in-place fp32

  char* ws = (char*)d_ws;
  const size_t SZ_C  = NST * 4;                       // 8,388,608
  const size_t SZ_H  = (size_t)Bv * PH * PH * HID * 2;  // 4,460,544
  const size_t SZ_X  = (size_t)Bv * PH * PH * 32 * 2;   // 2,230,272
  float*          c0  = (float*)ws;
  unsigned short* h0a = (unsigned short*)(ws + SZ_C);
  unsigned short* h0b = (unsigned short*)(ws + SZ_C + SZ_H);
  unsigned short* h1a = (unsigned short*)(ws + SZ_C + 2 * SZ_H);
  unsigned short* h1b = (unsigned short*)(ws + SZ_C + 3 * SZ_H);
  unsigned short* xb  = (unsigned short*)(ws + SZ_C + 4 * SZ_H);
  unsigned short* w0r = (unsigned short*)(ws + SZ_C + 4 * SZ_H + SZ_X);
  unsigned short* w1r = (unsigned short*)(ws + SZ_C + 4 * SZ_H + SZ_X + 27 * 8192 * 2);

  // zero c0 + h buffers (t=0 state & halos) + x halo; zero c1 in d_out
  hipMemsetAsync(ws, 0, SZ_C + 4 * SZ_H + SZ_X, stream);
  hipMemsetAsync(c1, 0, SZ_C, stream);

  relayout_w0<<<864, 256, 0, stream>>>(W0, w0r);
  relayout_w1<<<1152, 256, 0, stream>>>(W1, w1r);

  dim3 grid(Wv / 8, Hv / 16, Bv), block(512);
  for (int t = 0; t < Tv; ++t) {
    convert_x<<<128, 256, 0, stream>>>(enc + (size_t)t * Hv * Wv * Cv, xb);
    unsigned short* h0r = (t & 1) ? h0b : h0a;
    unsigned short* h0w = (t & 1) ? h0a : h0b;
    unsigned short* h1r = (t & 1) ? h1b : h1a;
    unsigned short* h1w = (t & 1) ? h1a : h1b;
    cell_mfma<0><<<grid, block, 0, stream>>>(xb, h0r, w0r, b0, c0, h0w, nullptr);
    cell_mfma<1><<<grid, block, 0, stream>>>(h0w, h1r, w1r, b1, c1, h1w,
                                             (t == Tv - 1) ? h1f : nullptr);
  }
}

// Round 3
// 1589.624 us; speedup vs baseline: 6.5500x; 1.0761x over previous
//
#include <hip/hip_runtime.h>
#include <hip/hip_bf16.h>

#define Bv 8
#define Tv 16
#define Hv 64
#define Wv 64
#define Cv 16
#define HID 64
#define PH 66   // spatially padded (1-px halo)

typedef short short8 __attribute__((ext_vector_type(8)));
typedef float f32x4 __attribute__((ext_vector_type(4)));
typedef unsigned short u16x8 __attribute__((ext_vector_type(8)));

__device__ __forceinline__ unsigned short f2bf(float x) {
  union { float f; unsigned int u; } v; v.f = x;
  unsigned int r = v.u + 0x7FFF + ((v.u >> 16) & 1);   // RNE
  return (unsigned short)(r >> 16);
}
__device__ __forceinline__ float sigmoid_f(float x) {
  return 1.f / (1.f + __expf(-x));
}
__device__ __forceinline__ float tanh_f(float x) {
  float e = __expf(2.f * x);
  return 1.f - 2.f / (e + 1.f);
}

// ---- x pre-convert: enc[b,t,y,x,0:16] fp32 -> padded bf16 [b][66][66][32] (ch16..31 = 0)
__global__ void convert_x(const float* __restrict__ enc_t, unsigned short* __restrict__ xb) {
  int idx = blockIdx.x * 256 + threadIdx.x;          // 32768 = b*4096 + pix
  int b = idx >> 12, pix = idx & 4095;
  int y = pix >> 6, x = pix & 63;
  const float* s = enc_t + (size_t)b * (Tv * Hv * Wv * Cv) + (size_t)pix * Cv;
  float4 f0 = *(const float4*)(s);
  float4 f1 = *(const float4*)(s + 4);
  float4 f2 = *(const float4*)(s + 8);
  float4 f3 = *(const float4*)(s + 12);
  u16x8 o0, o1, z = {};
  o0[0]=f2bf(f0.x); o0[1]=f2bf(f0.y); o0[2]=f2bf(f0.z); o0[3]=f2bf(f0.w);
  o0[4]=f2bf(f1.x); o0[5]=f2bf(f1.y); o0[6]=f2bf(f1.z); o0[7]=f2bf(f1.w);
  o1[0]=f2bf(f2.x); o1[1]=f2bf(f2.y); o1[2]=f2bf(f2.z); o1[3]=f2bf(f2.w);
  o1[4]=f2bf(f3.x); o1[5]=f2bf(f3.y); o1[6]=f2bf(f3.z); o1[7]=f2bf(f3.w);
  unsigned short* d = xb + ((size_t)((b * PH + y + 1) * PH) + (x + 1)) * 32;
  *(u16x8*)(d)      = o0;
  *(u16x8*)(d + 8)  = o1;
  *(u16x8*)(d + 16) = z;
  *(u16x8*)(d + 24) = z;
}

// ---- weight re-layouts: fp32 [3,3,CI,256] -> bf16 [chunk][col'][32]
// col' = wn*64 + g*16 + c  <->  orig col = g*64 + wn*16 + c   (wave-local gate fusion)
__global__ void relayout_w0(const float* __restrict__ W0, unsigned short* __restrict__ out) {
  int o = blockIdx.x * 256 + threadIdx.x;            // 27*8192 = 221184
  if (o >= 27 * 8192) return;
  int chunk = o >> 13, rem = o & 8191;
  int colp = rem >> 5, kk = rem & 31;
  int tap = chunk / 3, cg = chunk - tap * 3;
  int wn = colp >> 6, g = (colp >> 4) & 3, c = colp & 15;
  int col = g * 64 + wn * 16 + c;
  int p = cg * 32 + kk;                              // padded ci: 0..15 x, 16..31 pad, 32..95 h
  float v = 0.f;
  if (p < 16)        v = W0[(size_t)(tap * 80 + p) * 256 + col];
  else if (p >= 32)  v = W0[(size_t)(tap * 80 + (p - 16)) * 256 + col];
  out[o] = f2bf(v);
}
__global__ void relayout_w1(const float* __restrict__ W1, unsigned short* __restrict__ out) {
  int o = blockIdx.x * 256 + threadIdx.x;            // 36*8192 = 294912
  if (o >= 36 * 8192) return;
  int chunk = o >> 13, rem = o & 8191;
  int colp = rem >> 5, kk = rem & 31;
  int tap = chunk >> 2, cg = chunk & 3;
  int wn = colp >> 6, g = (colp >> 4) & 3, c = colp & 15;
  int col = g * 64 + wn * 16 + c;
  out[o] = f2bf(W1[(size_t)(tap * 128 + cg * 32 + kk) * 256 + col]);
}

// ---- fused ConvLSTM cell step: implicit-GEMM MFMA + gates.
// Block: 128 pixels (16x8 tile) x 256 gate-cols, 8 waves (wave = 64 px x 16 hid x 4 gates).
// CELL=0: A0 = x_bf (32ch), A1 = h0 (64ch), 27 chunks.
// CELL=1: A0 = h0 (64ch),  A1 = h1 (64ch), 36 chunks.
// Depth-3 register prefetch ring: chunk cc's loads issued 2 chunks before use.
template<int CELL>
__global__ __launch_bounds__(512, 2)
void cell_mfma(const unsigned short* __restrict__ A0, const unsigned short* __restrict__ A1,
               const unsigned short* __restrict__ Wr, const float* __restrict__ bias,
               float* __restrict__ cbuf, unsigned short* __restrict__ hout,
               float* __restrict__ hf32) {
  constexpr int CG = (CELL == 0) ? 3 : 4;
  constexpr int NC = 9 * CG;

  const int tid = threadIdx.x;
  const int l = tid & 63, w = tid >> 6;
  const int wm = w >> 2, wn = w & 3;
  const int bx = blockIdx.x, by = blockIdx.y, b = blockIdx.z;
  const int r = l & 15, kg = l >> 4;

  const char* bases[2] = {(const char*)A0, (const char*)A1};
  unsigned int offs[CG][4];
#pragma unroll
  for (int mi = 0; mi < 4; ++mi) {
    int p = wm * 64 + mi * 16 + r;
    int y = by * 16 + (p >> 3), x = bx * 8 + (p & 7);
    int pix = (b * PH + y) * PH + x;                 // tap(0,0) in padded coords
#pragma unroll
    for (int cg = 0; cg < CG; ++cg) {
      int chb = (CELL == 0) ? (cg == 0 ? 64 : 128) : 128;   // bytes per pixel-row
      int cho = (CELL == 0) ? (cg == 2 ? 64 : 0) : ((cg & 1) * 64);
      offs[cg][mi] = (unsigned)(pix * chb + cho + kg * 16);
    }
  }
  const unsigned int boff = (unsigned)((wn * 64 + r) * 64 + kg * 16);

  // ---- early independent loads: bias + c-state (consumed after the GEMM)
  const int j = wn * 16 + r;
  float bi[4];
#pragma unroll
  for (int g = 0; g < 4; ++g) bi[g] = bias[g * 64 + j];
  float cpre[4][4];
#pragma unroll
  for (int mi = 0; mi < 4; ++mi) {
#pragma unroll
    for (int rg = 0; rg < 4; ++rg) {
      int p = wm * 64 + mi * 16 + kg * 4 + rg;
      int y = by * 16 + (p >> 3), x = bx * 8 + (p & 7);
      cpre[mi][rg] = cbuf[((size_t)((b * Hv + y) * Wv) + x) * HID + j];
    }
  }

  f32x4 acc[4][4] = {};
  short8 af[3][4], bfv[3][4];

  auto LD = [&](int cc, int pp) {
    int tap = cc / CG, cg = cc - tap * CG;
    int ky = tap / 3, kx = tap - ky * 3;
    int chb = (CELL == 0) ? (cg == 0 ? 64 : 128) : 128;
    int bs  = (CELL == 0) ? (cg == 0 ? 0 : 1) : (cg >> 1);
    unsigned int toff = (unsigned)((ky * PH + kx) * chb);
#pragma unroll
    for (int mi = 0; mi < 4; ++mi)
      af[pp][mi] = *(const short8*)(bases[bs] + offs[cg][mi] + toff);
    const char* wp = (const char*)Wr + (size_t)cc * 16384 + boff;
#pragma unroll
    for (int g = 0; g < 4; ++g)
      bfv[pp][g] = *(const short8*)(wp + g * 1024);
  };

  LD(0, 0);
  LD(1, 1);
#pragma unroll
  for (int cc = 0; cc < NC; ++cc) {
    if (cc + 2 < NC) LD(cc + 2, (cc + 2) % 3);
    const int pp = cc % 3;
#pragma unroll
    for (int mi = 0; mi < 4; ++mi)
#pragma unroll
      for (int g = 0; g < 4; ++g)
        acc[mi][g] = __builtin_amdgcn_mfma_f32_16x16x32_bf16(
            af[pp][mi], bfv[pp][g], acc[mi][g], 0, 0, 0);
  }

  // ---- gates (wave-local: this wave owns hid j = wn*16 + r, all 4 gates)
#pragma unroll
  for (int mi = 0; mi < 4; ++mi) {
#pragma unroll
    for (int rg = 0; rg < 4; ++rg) {
      int p = wm * 64 + mi * 16 + kg * 4 + rg;       // C/D row = (lane>>4)*4 + reg
      int y = by * 16 + (p >> 3), x = bx * 8 + (p & 7);
      size_t ci = ((size_t)((b * Hv + y) * Wv) + x) * HID + j;
      float zi = acc[mi][0][rg] + bi[0];
      float zf = acc[mi][1][rg] + bi[1];
      float zo = acc[mi][2][rg] + bi[2];
      float zg = acc[mi][3][rg] + bi[3];
      float co = cpre[mi][rg];
      float cn = sigmoid_f(zf) * co + sigmoid_f(zi) * tanh_f(zg);
      float hn = sigmoid_f(zo) * tanh_f(cn);
      cbuf[ci] = cn;
      hout[((size_t)((b * PH + y + 1) * PH) + (x + 1)) * HID + j] = f2bf(hn);
      if (hf32) hf32[ci] = hn;
    }
  }
}

extern "C" void kernel_launch(void* const* d_in, const int* in_sizes, int n_in,
                              void* d_out, int out_size, void* d_ws, size_t ws_size,
                              hipStream_t stream) {
  const float* enc = (const float*)d_in[0];
  const float* W0  = (const float*)d_in[1];
  const float* b0  = (const float*)d_in[2];
  const float* W1  = (const float*)d_in[3];
  const float* b1  = (const float*)d_in[4];

  float* out = (float*)d_out;
  const size_t NST = (size_t)Bv * Hv * Wv * HID;     // 2,097,152
  float* h1f = out;                                   // final h1 (fp32)
  float* c1  = out + NST;                             // c1 state, in-place fp32

  char* ws = (char*)d_ws;
  const size_t SZ_C  = NST * 4;                       // 8,388,608
  const size_t SZ_H  = (size_t)Bv * PH * PH * HID * 2;  // 4,460,544
  const size_t SZ_X  = (size_t)Bv * PH * PH * 32 * 2;   // 2,230,272
  float*          c0  = (float*)ws;
  unsigned short* h0a = (unsigned short*)(ws + SZ_C);
  unsigned short* h0b = (unsigned short*)(ws + SZ_C + SZ_H);
  unsigned short* h1a = (unsigned short*)(ws + SZ_C + 2 * SZ_H);
  unsigned short* h1b = (unsigned short*)(ws + SZ_C + 3 * SZ_H);
  unsigned short* xb  = (unsigned short*)(ws + SZ_C + 4 * SZ_H);
  unsigned short* w0r = (unsigned short*)(ws + SZ_C + 4 * SZ_H + SZ_X);
  unsigned short* w1r = (unsigned short*)(ws + SZ_C + 4 * SZ_H + SZ_X + 27 * 8192 * 2);

  // zero c0 + h buffers (t=0 state & halos) + x halo; zero c1 in d_out
  hipMemsetAsync(ws, 0, SZ_C + 4 * SZ_H + SZ_X, stream);
  hipMemsetAsync(c1, 0, SZ_C, stream);

  relayout_w0<<<864, 256, 0, stream>>>(W0, w0r);
  relayout_w1<<<1152, 256, 0, stream>>>(W1, w1r);

  dim3 grid(Wv / 8, Hv / 16, Bv), block(512);
  for (int t = 0; t < Tv; ++t) {
    convert_x<<<128, 256, 0, stream>>>(enc + (size_t)t * Hv * Wv * Cv, xb);
    unsigned short* h0r = (t & 1) ? h0b : h0a;
    unsigned short* h0w = (t & 1) ? h0a : h0b;
    unsigned short* h1r = (t & 1) ? h1b : h1a;
    unsigned short* h1w = (t & 1) ? h1a : h1b;
    cell_mfma<0><<<grid, block, 0, stream>>>(xb, h0r, w0r, b0, c0, h0w, nullptr);
    cell_mfma<1><<<grid, block, 0, stream>>>(h0w, h1r, w1r, b1, c1, h1w,
                                             (t == Tv - 1) ? h1f : nullptr);
  }
}